// Round 5
// baseline (242.936 us; speedup 1.0000x reference)
//
#include <hip/hip_runtime.h>

#define NN   4096
#define FIN  512
#define FOUT 256
#define ALPHA 0.2f

typedef __attribute__((ext_vector_type(8))) short short8;
typedef __attribute__((ext_vector_type(4))) float f32x4;
typedef unsigned short u16;

__device__ __forceinline__ u16 f2bf(float x) {   // round-to-nearest-even
    union { float f; unsigned u; } v; v.f = x;
    unsigned r = v.u + 0x7FFF + ((v.u >> 16) & 1);
    return (u16)(r >> 16);
}

// ---------------- Kernel 0: Wt[f][k] bf16 = transpose(W [k][f] fp32) ----------------
__global__ __launch_bounds__(256) void k_wt(const float* __restrict__ W,
                                            u16* __restrict__ Wt) {
    __shared__ float s[64 * 65];
    const int t  = threadIdx.x;
    const int f0 = blockIdx.x * 64;
    const int k0 = blockIdx.y * 64;
    #pragma unroll
    for (int p = 0; p < 4; ++p) {
        int q = t + 256 * p, rr = q >> 4, cc = q & 15;
        float4 w4 = *(const float4*)&W[(size_t)(k0 + rr) * FOUT + f0 + cc * 4];
        s[(cc * 4 + 0) * 65 + rr] = w4.x;
        s[(cc * 4 + 1) * 65 + rr] = w4.y;
        s[(cc * 4 + 2) * 65 + rr] = w4.z;
        s[(cc * 4 + 3) * 65 + rr] = w4.w;
    }
    __syncthreads();
    #pragma unroll
    for (int p = 0; p < 4; ++p) {
        int q = t + 256 * p, f = q >> 4, kg = q & 15;
        ushort4 o;
        o.x = f2bf(s[f * 65 + kg * 4 + 0]);
        o.y = f2bf(s[f * 65 + kg * 4 + 1]);
        o.z = f2bf(s[f * 65 + kg * 4 + 2]);
        o.w = f2bf(s[f * 65 + kg * 4 + 3]);
        *(ushort4*)&Wt[(size_t)(f0 + f) * FIN + k0 + kg * 4] = o;
    }
}

// ------- Kernel 1: whT bf16 tiles + partial f_src/f_dst + counter init -------
// Block: 32 i x 64 f, grid (4, 128). Stage h slab once; Wt B-frags from L2.
// whT layout: [j/32][f][j&31] bf16. psrc/pdst[fb][i]: partial dots over 64-f slab.
#define HS 520   // u16 LDS row stride
__global__ __launch_bounds__(256) void k_proj(const float* __restrict__ h,
                                              const u16* __restrict__ Wt,
                                              const float* __restrict__ bias,
                                              const float* __restrict__ a1,
                                              const float* __restrict__ a2,
                                              u16* __restrict__ whT,
                                              float* __restrict__ psrc,
                                              float* __restrict__ pdst,
                                              int* __restrict__ counters) {
    __shared__ u16   s_h[32 * HS];     // 32 x 512 bf16
    __shared__ float s_red[4 * 32];    // [(sd*2+fh)][i_local]
    const int t  = threadIdx.x;
    const int f0 = blockIdx.x * 64;
    const int i0 = blockIdx.y * 32;
    if (blockIdx.x == 0 && t == 0) counters[blockIdx.y] = 0;   // for k_attn's decoupled combine
    #pragma unroll
    for (int p = 0; p < 16; ++p) {
        int q = t + 256 * p, row = q >> 7, c4 = q & 127;
        float4 v = *(const float4*)&h[(size_t)(i0 + row) * FIN + c4 * 4];
        ushort4 o; o.x = f2bf(v.x); o.y = f2bf(v.y); o.z = f2bf(v.z); o.w = f2bf(v.w);
        *(ushort4*)&s_h[row * HS + c4 * 4] = o;
    }
    __syncthreads();
    const int w = t >> 6, l = t & 63, n = l & 15, quad = l >> 4;
    const int hh = w & 1, fh = w >> 1;
    f32x4 acc[2] = {{0.f,0.f,0.f,0.f},{0.f,0.f,0.f,0.f}};
    #pragma unroll
    for (int k0 = 0; k0 < FIN; k0 += 32) {
        short8 a  = *(const short8*)&s_h[(hh * 16 + n) * HS + k0 + quad * 8];
        short8 b0 = *(const short8*)&Wt[(size_t)(f0 + fh * 32 + n) * FIN + k0 + quad * 8];
        short8 b1 = *(const short8*)&Wt[(size_t)(f0 + fh * 32 + 16 + n) * FIN + k0 + quad * 8];
        acc[0] = __builtin_amdgcn_mfma_f32_16x16x32_bf16(a, b0, acc[0], 0, 0, 0);
        acc[1] = __builtin_amdgcn_mfma_f32_16x16x32_bf16(a, b1, acc[1], 0, 0, 0);
    }
    u16* wt_tile = whT + (size_t)(i0 >> 5) * (FOUT * 32);
    float a1v[2], a2v[2];
    a1v[0] = a1[f0 + fh * 32 + n];      a1v[1] = a1[f0 + fh * 32 + 16 + n];
    a2v[0] = a2[f0 + fh * 32 + n];      a2v[1] = a2[f0 + fh * 32 + 16 + n];
    float ps[4] = {0.f,0.f,0.f,0.f}, pd[4] = {0.f,0.f,0.f,0.f};
    #pragma unroll
    for (int u = 0; u < 2; ++u) {
        const int f = f0 + fh * 32 + u * 16 + n;
        const float bv = bias[f];
        #pragma unroll
        for (int r = 0; r < 4; ++r) {
            float val = acc[u][r] + bv;                      // D: row=quad*4+r, col=n
            wt_tile[f * 32 + hh * 16 + quad * 4 + r] = f2bf(val);
            ps[r] += val * a1v[u];
            pd[r] += val * a2v[u];
        }
    }
    #pragma unroll
    for (int m = 1; m < 16; m <<= 1) {        // reduce over the 16 n-lanes
        #pragma unroll
        for (int r = 0; r < 4; ++r) { ps[r] += __shfl_xor(ps[r], m); pd[r] += __shfl_xor(pd[r], m); }
    }
    if (n == 0) {
        #pragma unroll
        for (int r = 0; r < 4; ++r) {
            int il = hh * 16 + quad * 4 + r;
            s_red[fh * 32 + il]       = ps[r];
            s_red[64 + fh * 32 + il]  = pd[r];
        }
    }
    __syncthreads();
    if (t < 32) {
        psrc[(size_t)blockIdx.x * NN + i0 + t] = s_red[t]      + s_red[32 + t];
        pdst[(size_t)blockIdx.x * NN + i0 + t] = s_red[64 + t] + s_red[96 + t];
    }
}

// ------ Kernel 2: fused mask+exp + MFMA P@wh + decoupled combine/elu ------
#define BI 32
#define TJ 64
#define PS 72
__global__ __launch_bounds__(256) void k_attn(const int* __restrict__ adj,
                                              const u16* __restrict__ whT,
                                              const float* __restrict__ psrc,
                                              const float* __restrict__ pdst,
                                              const float* __restrict__ ab,
                                              float* __restrict__ part,
                                              float* __restrict__ psum,
                                              int* __restrict__ counters,
                                              float* __restrict__ out) {
    __shared__ u16   s_p[BI * PS];
    __shared__ float s_fd[NN];         // up to 16 KB; jchunk used
    __shared__ float s_fs[BI];
    __shared__ int   s_win;
    const int t  = threadIdx.x;
    const int i0 = blockIdx.x * BI;
    const int c  = blockIdx.y;
    const int jchunk = NN / gridDim.y;
    const int jbeg = c * jchunk, jend = jbeg + jchunk;
    const int jq = t & 15, rh = t >> 4;
    const int w = t >> 6, l = t & 63, n = l & 15, quad = l >> 4;

    // ---- preamble: fs (32 rows) and fd (chunk) from the 4 f-slab partials ----
    if (t < BI) {
        s_fs[t] = psrc[i0 + t] + psrc[NN + i0 + t] + psrc[2 * NN + i0 + t]
                + psrc[3 * NN + i0 + t] + ab[0];
    }
    for (int q = t; q < (jchunk >> 2); q += 256) {
        float4 v0 = ((const float4*)&pdst[jbeg])[q];
        float4 v1 = ((const float4*)&pdst[NN + jbeg])[q];
        float4 v2 = ((const float4*)&pdst[2 * NN + jbeg])[q];
        float4 v3 = ((const float4*)&pdst[3 * NN + jbeg])[q];
        float4 o;
        o.x = v0.x + v1.x + v2.x + v3.x; o.y = v0.y + v1.y + v2.y + v3.y;
        o.z = v0.z + v1.z + v2.z + v3.z; o.w = v0.w + v1.w + v2.w + v3.w;
        ((float4*)s_fd)[q] = o;
    }
    __syncthreads();
    const float fs0 = s_fs[rh], fs1 = s_fs[rh + 16];

    f32x4 acc[2][4] = {{{0.f,0.f,0.f,0.f},{0.f,0.f,0.f,0.f},{0.f,0.f,0.f,0.f},{0.f,0.f,0.f,0.f}},
                       {{0.f,0.f,0.f,0.f},{0.f,0.f,0.f,0.f},{0.f,0.f,0.f,0.f},{0.f,0.f,0.f,0.f}}};
    float rs0 = 0.f, rs1 = 0.f;
    int4 av0 = *(const int4*)&adj[(size_t)(i0 + rh) * NN + jbeg + jq * 4];
    int4 av1 = *(const int4*)&adj[(size_t)(i0 + rh + 16) * NN + jbeg + jq * 4];

    for (int j0 = jbeg; j0 < jend; j0 += TJ) {
        float4 fdv = *(const float4*)&s_fd[(j0 - jbeg) + jq * 4];
        ushort4 o0, o1;
        {
            float x, p;
            x = fs0 + fdv.x; x = x > 0.f ? x : ALPHA * x; p = av0.x > 0 ? __expf(x) : 0.f; o0.x = f2bf(p); rs0 += p;
            x = fs0 + fdv.y; x = x > 0.f ? x : ALPHA * x; p = av0.y > 0 ? __expf(x) : 0.f; o0.y = f2bf(p); rs0 += p;
            x = fs0 + fdv.z; x = x > 0.f ? x : ALPHA * x; p = av0.z > 0 ? __expf(x) : 0.f; o0.z = f2bf(p); rs0 += p;
            x = fs0 + fdv.w; x = x > 0.f ? x : ALPHA * x; p = av0.w > 0 ? __expf(x) : 0.f; o0.w = f2bf(p); rs0 += p;
            x = fs1 + fdv.x; x = x > 0.f ? x : ALPHA * x; p = av1.x > 0 ? __expf(x) : 0.f; o1.x = f2bf(p); rs1 += p;
            x = fs1 + fdv.y; x = x > 0.f ? x : ALPHA * x; p = av1.y > 0 ? __expf(x) : 0.f; o1.y = f2bf(p); rs1 += p;
            x = fs1 + fdv.z; x = x > 0.f ? x : ALPHA * x; p = av1.z > 0 ? __expf(x) : 0.f; o1.z = f2bf(p); rs1 += p;
            x = fs1 + fdv.w; x = x > 0.f ? x : ALPHA * x; p = av1.w > 0 ? __expf(x) : 0.f; o1.w = f2bf(p); rs1 += p;
        }
        __syncthreads();   // prev-iter MFMA done with s_p
        *(ushort4*)&s_p[rh * PS + jq * 4]        = o0;
        *(ushort4*)&s_p[(rh + 16) * PS + jq * 4] = o1;
        if (j0 + TJ < jend) {   // prefetch next adj off the critical path
            av0 = *(const int4*)&adj[(size_t)(i0 + rh) * NN + j0 + TJ + jq * 4];
            av1 = *(const int4*)&adj[(size_t)(i0 + rh + 16) * NN + j0 + TJ + jq * 4];
        }
        short8 b[2][4];
        #pragma unroll
        for (int s = 0; s < 2; ++s) {
            const u16* tb = whT + (size_t)((j0 >> 5) + s) * (FOUT * 32) + quad * 8;
            #pragma unroll
            for (int u = 0; u < 4; ++u)
                b[s][u] = *(const short8*)&tb[(w * 64 + u * 16 + n) * 32];
        }
        __syncthreads();   // s_p visible
        #pragma unroll
        for (int s = 0; s < 2; ++s) {
            short8 a0  = *(const short8*)&s_p[n * PS + s * 32 + quad * 8];
            short8 a1f = *(const short8*)&s_p[(16 + n) * PS + s * 32 + quad * 8];
            #pragma unroll
            for (int u = 0; u < 4; ++u) {
                acc[0][u] = __builtin_amdgcn_mfma_f32_16x16x32_bf16(a0,  b[s][u], acc[0][u], 0, 0, 0);
                acc[1][u] = __builtin_amdgcn_mfma_f32_16x16x32_bf16(a1f, b[s][u], acc[1][u], 0, 0, 0);
            }
        }
    }
    // ---- partial denominators ----
    #pragma unroll
    for (int m = 8; m > 0; m >>= 1) {
        rs0 += __shfl_xor(rs0, m);
        rs1 += __shfl_xor(rs1, m);
    }
    if (jq == 0) {
        psum[(size_t)c * NN + i0 + rh]      = rs0;
        psum[(size_t)c * NN + i0 + rh + 16] = rs1;
    }
    // ---- partial numerators ----
    float* pc = part + ((size_t)c * NN + i0) * FOUT;
    #pragma unroll
    for (int hf = 0; hf < 2; ++hf)
        #pragma unroll
        for (int u = 0; u < 4; ++u)
            #pragma unroll
            for (int r = 0; r < 4; ++r)
                pc[(size_t)(hf * 16 + quad * 4 + r) * FOUT + w * 64 + u * 16 + n] = acc[hf][u][r];

    // ---- decoupled combine: last chunk to finish this i-block does the epilogue ----
    __threadfence();
    if (t == 0) s_win = (atomicAdd(&counters[blockIdx.x], 1) == (int)gridDim.y - 1) ? 1 : 0;
    __syncthreads();
    if (s_win) {
        __threadfence();
        const int Cn = gridDim.y;
        const size_t s4 = (size_t)NN * (FOUT / 4);
        const float4* p4 = (const float4*)part;
        for (int p = 0; p < 8; ++p) {
            const int q = t + 256 * p;          // 0..2047
            const int il = q >> 6;
            const size_t g = (size_t)(i0 + il) * (FOUT / 4) + (q & 63);
            float4 a = p4[g];
            float s = psum[i0 + il];
            for (int cc = 1; cc < Cn; ++cc) {
                float4 bb = p4[g + (size_t)cc * s4];
                a.x += bb.x; a.y += bb.y; a.z += bb.z; a.w += bb.w;
                s += psum[(size_t)cc * NN + i0 + il];
            }
            const float inv = 1.0f / s;
            a.x *= inv; a.y *= inv; a.z *= inv; a.w *= inv;
            a.x = a.x > 0.f ? a.x : __expf(a.x) - 1.f;
            a.y = a.y > 0.f ? a.y : __expf(a.y) - 1.f;
            a.z = a.z > 0.f ? a.z : __expf(a.z) - 1.f;
            a.w = a.w > 0.f ? a.w : __expf(a.w) - 1.f;
            ((float4*)out)[g] = a;
        }
    }
}

extern "C" void kernel_launch(void* const* d_in, const int* in_sizes, int n_in,
                              void* d_out, int out_size, void* d_ws, size_t ws_size,
                              hipStream_t stream) {
    const int*   adj = (const int*)  d_in[0];
    const float* h   = (const float*)d_in[1];
    const float* W   = (const float*)d_in[2];
    const float* b   = (const float*)d_in[3];
    const float* a1  = (const float*)d_in[4];
    const float* a2  = (const float*)d_in[5];
    const float* ab  = (const float*)d_in[6];
    float* out = (float*)d_out;

    auto need = [](int c) -> size_t {
        size_t fl = 8 * (size_t)NN + (size_t)c * NN + (size_t)c * NN * FOUT + 128;
        size_t us = (size_t)FOUT * FIN + (size_t)NN * FOUT;   // Wt + whT bf16
        return fl * 4 + us * 2;
    };
    int C = 4;
    while (C > 1 && need(C) > ws_size) C >>= 1;

    float* psrc = (float*)d_ws;                       // [4][NN]
    float* pdst = psrc + 4 * (size_t)NN;              // [4][NN]
    float* psum = pdst + 4 * (size_t)NN;              // [C][NN]
    float* part = psum + (size_t)C * NN;              // [C][NN][FOUT]
    int*   counters = (int*)(part + (size_t)C * NN * FOUT);   // [128]
    u16*   Wt  = (u16*)(counters + 128);              // [FOUT][FIN]
    u16*   whT = Wt + (size_t)FOUT * FIN;             // [NN/32][FOUT][32]

    k_wt  <<<dim3(FOUT / 64, FIN / 64), 256, 0, stream>>>(W, Wt);
    k_proj<<<dim3(FOUT / 64, NN / 32), 256, 0, stream>>>(h, Wt, b, a1, a2, whT, psrc, pdst, counters);
    k_attn<<<dim3(NN / BI, C), 256, 0, stream>>>(adj, whT, psrc, pdst, ab, part, psum, counters, out);
}

// Round 6
// 165.636 us; speedup vs baseline: 1.4667x; 1.4667x over previous
//
#include <hip/hip_runtime.h>

#define NN   4096
#define FIN  512
#define FOUT 256
#define ALPHA 0.2f

typedef __attribute__((ext_vector_type(8))) short short8;
typedef __attribute__((ext_vector_type(4))) float f32x4;
typedef unsigned short u16;

__device__ __forceinline__ u16 f2bf(float x) {   // round-to-nearest-even
    union { float f; unsigned u; } v; v.f = x;
    unsigned r = v.u + 0x7FFF + ((v.u >> 16) & 1);
    return (u16)(r >> 16);
}

// ---------------- Kernel 0: Wt[f][k] bf16 = transpose(W [k][f] fp32) ----------------
__global__ __launch_bounds__(256) void k_wt(const float* __restrict__ W,
                                            u16* __restrict__ Wt) {
    __shared__ float s[64 * 65];
    const int t  = threadIdx.x;
    const int f0 = blockIdx.x * 64;
    const int k0 = blockIdx.y * 64;
    #pragma unroll
    for (int p = 0; p < 4; ++p) {
        int q = t + 256 * p, rr = q >> 4, cc = q & 15;
        float4 w4 = *(const float4*)&W[(size_t)(k0 + rr) * FOUT + f0 + cc * 4];
        s[(cc * 4 + 0) * 65 + rr] = w4.x;
        s[(cc * 4 + 1) * 65 + rr] = w4.y;
        s[(cc * 4 + 2) * 65 + rr] = w4.z;
        s[(cc * 4 + 3) * 65 + rr] = w4.w;
    }
    __syncthreads();
    #pragma unroll
    for (int p = 0; p < 4; ++p) {
        int q = t + 256 * p, f = q >> 4, kg = q & 15;
        ushort4 o;
        o.x = f2bf(s[f * 65 + kg * 4 + 0]);
        o.y = f2bf(s[f * 65 + kg * 4 + 1]);
        o.z = f2bf(s[f * 65 + kg * 4 + 2]);
        o.w = f2bf(s[f * 65 + kg * 4 + 3]);
        *(ushort4*)&Wt[(size_t)(f0 + f) * FIN + k0 + kg * 4] = o;
    }
}

// ------- Kernel 1: whT bf16 tiles + partial f_src/f_dst (k_vec folded in) -------
// Block: 32 i x 64 f, grid (4, 128). Stage h slab once; Wt B-frags from L2.
// whT layout: [j/32][f][j&31] bf16. psrc/pdst[fb][i]: partial dots over 64-f slab.
#define HS 520   // u16 LDS row stride
__global__ __launch_bounds__(256) void k_proj(const float* __restrict__ h,
                                              const u16* __restrict__ Wt,
                                              const float* __restrict__ bias,
                                              const float* __restrict__ a1,
                                              const float* __restrict__ a2,
                                              u16* __restrict__ whT,
                                              float* __restrict__ psrc,
                                              float* __restrict__ pdst) {
    __shared__ u16   s_h[32 * HS];     // 32 x 512 bf16
    __shared__ float s_red[4 * 32];
    const int t  = threadIdx.x;
    const int f0 = blockIdx.x * 64;
    const int i0 = blockIdx.y * 32;
    #pragma unroll
    for (int p = 0; p < 16; ++p) {
        int q = t + 256 * p, row = q >> 7, c4 = q & 127;
        float4 v = *(const float4*)&h[(size_t)(i0 + row) * FIN + c4 * 4];
        ushort4 o; o.x = f2bf(v.x); o.y = f2bf(v.y); o.z = f2bf(v.z); o.w = f2bf(v.w);
        *(ushort4*)&s_h[row * HS + c4 * 4] = o;
    }
    __syncthreads();
    const int w = t >> 6, l = t & 63, n = l & 15, quad = l >> 4;
    const int hh = w & 1, fh = w >> 1;
    f32x4 acc[2] = {{0.f,0.f,0.f,0.f},{0.f,0.f,0.f,0.f}};
    #pragma unroll
    for (int k0 = 0; k0 < FIN; k0 += 32) {
        short8 a  = *(const short8*)&s_h[(hh * 16 + n) * HS + k0 + quad * 8];
        short8 b0 = *(const short8*)&Wt[(size_t)(f0 + fh * 32 + n) * FIN + k0 + quad * 8];
        short8 b1 = *(const short8*)&Wt[(size_t)(f0 + fh * 32 + 16 + n) * FIN + k0 + quad * 8];
        acc[0] = __builtin_amdgcn_mfma_f32_16x16x32_bf16(a, b0, acc[0], 0, 0, 0);
        acc[1] = __builtin_amdgcn_mfma_f32_16x16x32_bf16(a, b1, acc[1], 0, 0, 0);
    }
    u16* wt_tile = whT + (size_t)(i0 >> 5) * (FOUT * 32);
    float a1v[2], a2v[2];
    a1v[0] = a1[f0 + fh * 32 + n];      a1v[1] = a1[f0 + fh * 32 + 16 + n];
    a2v[0] = a2[f0 + fh * 32 + n];      a2v[1] = a2[f0 + fh * 32 + 16 + n];
    float ps[4] = {0.f,0.f,0.f,0.f}, pd[4] = {0.f,0.f,0.f,0.f};
    #pragma unroll
    for (int u = 0; u < 2; ++u) {
        const int f = f0 + fh * 32 + u * 16 + n;
        const float bv = bias[f];
        #pragma unroll
        for (int r = 0; r < 4; ++r) {
            float val = acc[u][r] + bv;                      // D: row=quad*4+r, col=n
            wt_tile[f * 32 + hh * 16 + quad * 4 + r] = f2bf(val);
            ps[r] += val * a1v[u];
            pd[r] += val * a2v[u];
        }
    }
    #pragma unroll
    for (int m = 1; m < 16; m <<= 1) {        // reduce over the 16 n-lanes
        #pragma unroll
        for (int r = 0; r < 4; ++r) { ps[r] += __shfl_xor(ps[r], m); pd[r] += __shfl_xor(pd[r], m); }
    }
    if (n == 0) {
        #pragma unroll
        for (int r = 0; r < 4; ++r) {
            int il = hh * 16 + quad * 4 + r;
            s_red[fh * 32 + il]       = ps[r];
            s_red[64 + fh * 32 + il]  = pd[r];
        }
    }
    __syncthreads();
    if (t < 32) {
        psrc[(size_t)blockIdx.x * NN + i0 + t] = s_red[t]      + s_red[32 + t];
        pdst[(size_t)blockIdx.x * NN + i0 + t] = s_red[64 + t] + s_red[96 + t];
    }
}

// ------ Kernel 2: fused mask+exp + MFMA P@wh -> partials (no fences) ------
// BI=32 rows/block, TJ=64 j/iter, C=8 chunks -> grid (128,8)=1024 blocks, 4/CU.
// Double-buffered s_p: ONE barrier per iter; adj/B-frag loads issued AFTER the
// barrier so the barrier's vmcnt(0) drain is nearly empty (latency lands on
// per-wave waits, hidden across the 16 resident waves).
#define BI 32
#define TJ 64
#define PS 72
#define CC 8
#define JCHUNK (NN / CC)          // 512
#define NITER  (JCHUNK / TJ)      // 8
__global__ __launch_bounds__(256) void k_attn(const int* __restrict__ adj,
                                              const u16* __restrict__ whT,
                                              const float* __restrict__ psrc,
                                              const float* __restrict__ pdst,
                                              const float* __restrict__ ab,
                                              float* __restrict__ part,
                                              float* __restrict__ psum) {
    __shared__ u16   s_p[2][BI * PS];  // double-buffered P tile
    __shared__ float s_fd[JCHUNK];
    __shared__ float s_fs[BI];
    const int t  = threadIdx.x;
    const int i0 = blockIdx.x * BI;
    const int c  = blockIdx.y;
    const int jbeg = c * JCHUNK;
    const int jq = t & 15, rh = t >> 4;
    const int w = t >> 6, l = t & 63, n = l & 15, quad = l >> 4;

    // ---- preamble: fs (32 rows) and fd (chunk) from the 4 f-slab partials ----
    if (t < BI) {
        s_fs[t] = psrc[i0 + t] + psrc[NN + i0 + t] + psrc[2 * NN + i0 + t]
                + psrc[3 * NN + i0 + t] + ab[0];
    }
    if (t < JCHUNK / 4) {
        float4 v0 = ((const float4*)&pdst[jbeg])[t];
        float4 v1 = ((const float4*)&pdst[NN + jbeg])[t];
        float4 v2 = ((const float4*)&pdst[2 * NN + jbeg])[t];
        float4 v3 = ((const float4*)&pdst[3 * NN + jbeg])[t];
        float4 o;
        o.x = v0.x + v1.x + v2.x + v3.x; o.y = v0.y + v1.y + v2.y + v3.y;
        o.z = v0.z + v1.z + v2.z + v3.z; o.w = v0.w + v1.w + v2.w + v3.w;
        ((float4*)s_fd)[t] = o;
    }
    __syncthreads();
    const float fs0 = s_fs[rh], fs1 = s_fs[rh + 16];

    f32x4 acc[2][4] = {{{0.f,0.f,0.f,0.f},{0.f,0.f,0.f,0.f},{0.f,0.f,0.f,0.f},{0.f,0.f,0.f,0.f}},
                       {{0.f,0.f,0.f,0.f},{0.f,0.f,0.f,0.f},{0.f,0.f,0.f,0.f},{0.f,0.f,0.f,0.f}}};
    float rs0 = 0.f, rs1 = 0.f;
    int4 av0 = *(const int4*)&adj[(size_t)(i0 + rh) * NN + jbeg + jq * 4];
    int4 av1 = *(const int4*)&adj[(size_t)(i0 + rh + 16) * NN + jbeg + jq * 4];

    for (int it = 0; it < NITER; ++it) {
        const int j0 = jbeg + it * TJ;
        u16* sp = s_p[it & 1];
        // ---- compute p from prefetched adj ----
        float4 fdv = *(const float4*)&s_fd[it * TJ + jq * 4];
        ushort4 o0, o1;
        {
            float x, p;
            x = fs0 + fdv.x; x = x > 0.f ? x : ALPHA * x; p = av0.x > 0 ? __expf(x) : 0.f; o0.x = f2bf(p); rs0 += p;
            x = fs0 + fdv.y; x = x > 0.f ? x : ALPHA * x; p = av0.y > 0 ? __expf(x) : 0.f; o0.y = f2bf(p); rs0 += p;
            x = fs0 + fdv.z; x = x > 0.f ? x : ALPHA * x; p = av0.z > 0 ? __expf(x) : 0.f; o0.z = f2bf(p); rs0 += p;
            x = fs0 + fdv.w; x = x > 0.f ? x : ALPHA * x; p = av0.w > 0 ? __expf(x) : 0.f; o0.w = f2bf(p); rs0 += p;
            x = fs1 + fdv.x; x = x > 0.f ? x : ALPHA * x; p = av1.x > 0 ? __expf(x) : 0.f; o1.x = f2bf(p); rs1 += p;
            x = fs1 + fdv.y; x = x > 0.f ? x : ALPHA * x; p = av1.y > 0 ? __expf(x) : 0.f; o1.y = f2bf(p); rs1 += p;
            x = fs1 + fdv.z; x = x > 0.f ? x : ALPHA * x; p = av1.z > 0 ? __expf(x) : 0.f; o1.z = f2bf(p); rs1 += p;
            x = fs1 + fdv.w; x = x > 0.f ? x : ALPHA * x; p = av1.w > 0 ? __expf(x) : 0.f; o1.w = f2bf(p); rs1 += p;
        }
        *(ushort4*)&sp[rh * PS + jq * 4]        = o0;
        *(ushort4*)&sp[(rh + 16) * PS + jq * 4] = o1;
        __syncthreads();   // drains only the ds_writes (loads below issue after)
        // ---- adj prefetch for next iter: in flight through the MFMA phase ----
        if (it + 1 < NITER) {
            av0 = *(const int4*)&adj[(size_t)(i0 + rh) * NN + j0 + TJ + jq * 4];
            av1 = *(const int4*)&adj[(size_t)(i0 + rh + 16) * NN + j0 + TJ + jq * 4];
        }
        // ---- B-frags from L2-hot whT ----
        short8 b[2][4];
        #pragma unroll
        for (int s = 0; s < 2; ++s) {
            const u16* tb = whT + (size_t)((j0 >> 5) + s) * (FOUT * 32) + quad * 8;
            #pragma unroll
            for (int u = 0; u < 4; ++u)
                b[s][u] = *(const short8*)&tb[(w * 64 + u * 16 + n) * 32];
        }
        // ---- MFMA phase ----
        #pragma unroll
        for (int s = 0; s < 2; ++s) {
            short8 a0  = *(const short8*)&sp[n * PS + s * 32 + quad * 8];
            short8 a1f = *(const short8*)&sp[(16 + n) * PS + s * 32 + quad * 8];
            #pragma unroll
            for (int u = 0; u < 4; ++u) {
                acc[0][u] = __builtin_amdgcn_mfma_f32_16x16x32_bf16(a0,  b[s][u], acc[0][u], 0, 0, 0);
                acc[1][u] = __builtin_amdgcn_mfma_f32_16x16x32_bf16(a1f, b[s][u], acc[1][u], 0, 0, 0);
            }
        }
    }
    // ---- partial denominators ----
    #pragma unroll
    for (int m = 8; m > 0; m >>= 1) {
        rs0 += __shfl_xor(rs0, m);
        rs1 += __shfl_xor(rs1, m);
    }
    if (jq == 0) {
        psum[(size_t)c * NN + i0 + rh]      = rs0;
        psum[(size_t)c * NN + i0 + rh + 16] = rs1;
    }
    // ---- partial numerators ----
    float* pc = part + ((size_t)c * NN + i0) * FOUT;
    #pragma unroll
    for (int hf = 0; hf < 2; ++hf)
        #pragma unroll
        for (int u = 0; u < 4; ++u)
            #pragma unroll
            for (int r = 0; r < 4; ++r)
                pc[(size_t)(hf * 16 + quad * 4 + r) * FOUT + w * 64 + u * 16 + n] = acc[hf][u][r];
}

// ------ Kernel 3: combine partials, normalize, elu ------
__global__ __launch_bounds__(256) void k_fin(const float* __restrict__ part,
                                             const float* __restrict__ psum,
                                             float* __restrict__ out) {
    const int g = blockIdx.x * 256 + threadIdx.x;
    const int i = g >> 6;
    const size_t s4 = (size_t)NN * (FOUT / 4);
    float4 a = ((const float4*)part)[g];
    float s = psum[i];
    #pragma unroll
    for (int c = 1; c < CC; ++c) {
        float4 bb = ((const float4*)part)[g + (size_t)c * s4];
        a.x += bb.x; a.y += bb.y; a.z += bb.z; a.w += bb.w;
        s += psum[(size_t)c * NN + i];
    }
    const float inv = 1.0f / s;
    a.x *= inv; a.y *= inv; a.z *= inv; a.w *= inv;
    a.x = a.x > 0.f ? a.x : __expf(a.x) - 1.f;
    a.y = a.y > 0.f ? a.y : __expf(a.y) - 1.f;
    a.z = a.z > 0.f ? a.z : __expf(a.z) - 1.f;
    a.w = a.w > 0.f ? a.w : __expf(a.w) - 1.f;
    ((float4*)out)[g] = a;
}

extern "C" void kernel_launch(void* const* d_in, const int* in_sizes, int n_in,
                              void* d_out, int out_size, void* d_ws, size_t ws_size,
                              hipStream_t stream) {
    const int*   adj = (const int*)  d_in[0];
    const float* h   = (const float*)d_in[1];
    const float* W   = (const float*)d_in[2];
    const float* b   = (const float*)d_in[3];
    const float* a1  = (const float*)d_in[4];
    const float* a2  = (const float*)d_in[5];
    const float* ab  = (const float*)d_in[6];
    float* out = (float*)d_out;

    // layout (floats unless noted): psrc[4][NN] | pdst[4][NN] | psum[CC][NN] |
    // part[CC][NN][FOUT] | Wt (u16) | whT (u16)  -- ~36 MB, ws observed ~268 MB.
    float* psrc = (float*)d_ws;
    float* pdst = psrc + 4 * (size_t)NN;
    float* psum = pdst + 4 * (size_t)NN;
    float* part = psum + (size_t)CC * NN;
    u16*   Wt   = (u16*)(part + (size_t)CC * NN * FOUT);
    u16*   whT  = Wt + (size_t)FOUT * FIN;

    k_wt  <<<dim3(FOUT / 64, FIN / 64), 256, 0, stream>>>(W, Wt);
    k_proj<<<dim3(FOUT / 64, NN / 32), 256, 0, stream>>>(h, Wt, b, a1, a2, whT, psrc, pdst);
    k_attn<<<dim3(NN / BI, CC), 256, 0, stream>>>(adj, whT, psrc, pdst, ab, part, psum);
    k_fin <<<(NN * FOUT / 4) / 256, 256, 0, stream>>>(part, psum, out);
}